// Round 14
// baseline (156.566 us; speedup 1.0000x reference)
//
#include <hip/hip_runtime.h>
#include <stdint.h>

#define N_SLOTS   65536
#define KEY_DIM   64
#define VAL_DIM   64
#define N_QUERIES 8192
#define TOPK      4
#define LR        1e-3f
#define MOMENTUM  0.9f
#define WD        1e-4f

#define NCHUNK 8
#define CHUNK  (N_SLOTS / NCHUNK)     /* 8192 slots per chunk */
#define TILE_SLOTS 128
#define TILES_PER_CHUNK (CHUNK / TILE_SLOTS)   /* 64 */
#define SUBT 8                         /* 8 subtiles of 16 slots per tile */
#define QPB 64                         /* 4 waves x 1 qtile x 16 */

/* kA_pack fused grid: zero | Q-pack | K-pack */
#define ZF4   ((N_SLOTS * VAL_DIM + N_SLOTS) / 4)   /* 1,064,960 float4 */
#define ZBLK  (ZF4 / 256)                            /* 4160 exactly */
#define QBLK  (N_QUERIES * 8 / 256)                  /* 256 */
#define KBLK  (N_SLOTS * 8 / 256)                    /* 2048 */

typedef __attribute__((ext_vector_type(8))) _Float16 f16x8;
typedef __attribute__((ext_vector_type(2))) __fp16   fp16x2;
typedef __attribute__((ext_vector_type(4))) float    f32x4;
union F16 { uint4 u; f16x8 h; };
union PK  { fp16x2 h2; uint32_t u; };

__device__ __forceinline__ uint32_t pk2(float a, float b) {
    PK p; p.h2 = __builtin_amdgcn_cvt_pkrtz(a, b); return p.u;
}

__device__ __forceinline__ uint32_t med3u(uint32_t a, uint32_t b, uint32_t c) {
    uint32_t d;
    asm("v_med3_u32 %0, %1, %2, %3" : "=v"(d) : "v"(a), "v"(b), "v"(c));
    return d;
}

__device__ __forceinline__ uint64_t ord64(double d) {
    uint64_t u = (uint64_t)__double_as_longlong(d);
    return (u & 0x8000000000000000ull) ? ~u : (u | 0x8000000000000000ull);
}
__device__ __forceinline__ void ins4(uint64_t* t, uint64_t key) {
    if (key > t[3]) {
        t[3] = key;
        if (t[3] > t[2]) { uint64_t x = t[2]; t[2] = t[3]; t[3] = x; }
        if (t[2] > t[1]) { uint64_t x = t[1]; t[1] = t[2]; t[2] = x; }
        if (t[1] > t[0]) { uint64_t x = t[0]; t[0] = t[1]; t[1] = x; }
    }
}
__device__ __forceinline__ void cswap64(uint64_t& x, uint64_t& y) {
    uint64_t hi = x > y ? x : y;
    uint64_t lo = x > y ? y : x;
    x = hi; y = lo;
}
__device__ __forceinline__ void merge4_64(uint64_t* a, uint64_t b0, uint64_t b1,
                                          uint64_t b2, uint64_t b3) {
    uint64_t m0 = a[0] > b3 ? a[0] : b3;
    uint64_t m1 = a[1] > b2 ? a[1] : b2;
    uint64_t m2 = a[2] > b1 ? a[2] : b1;
    uint64_t m3 = a[3] > b0 ? a[3] : b0;
    cswap64(m0, m2); cswap64(m1, m3); cswap64(m0, m1); cswap64(m2, m3);
    a[0] = m0; a[1] = m1; a[2] = m2; a[3] = m3;
}
__device__ __forceinline__ void cswap32(uint32_t& x, uint32_t& y) {
    uint32_t hi = max(x, y);
    uint32_t lo = min(x, y);
    x = hi; y = lo;
}
__device__ __forceinline__ void merge4_32(uint32_t* a, uint32_t b0, uint32_t b1,
                                          uint32_t b2, uint32_t b3) {
    uint32_t m0 = max(a[0], b3);
    uint32_t m1 = max(a[1], b2);
    uint32_t m2 = max(a[2], b1);
    uint32_t m3 = max(a[3], b0);
    cswap32(m0, m2); cswap32(m1, m3); cswap32(m0, m1); cswap32(m2, m3);
    a[0] = m0; a[1] = m1; a[2] = m2; a[3] = m3;
}

__device__ __forceinline__ void gload16(const void* g, void* l) {
    __builtin_amdgcn_global_load_lds(
        (const __attribute__((address_space(1))) uint32_t*)g,
        (__attribute__((address_space(3))) uint32_t*)l, 16, 0, 0);
}

// ---- fused: zero slot_grads/counts + f32->f16 pack (Q row-major, K swizzled) ----
// kpack unit = tile*1024 + r*8 + (k8 ^ (r&7)),  tile = slot/128, r = slot%128
__global__ void kA_pack(const float* __restrict__ queries,
                        const float* __restrict__ keys,
                        uint4* __restrict__ qpack, uint4* __restrict__ kpack,
                        float4* __restrict__ zbuf) {
    const int b = blockIdx.x, tid = threadIdx.x;
    if (b < ZBLK) {                             // zero slot_grads + counts
        zbuf[b * 256 + tid] = (float4){0.f, 0.f, 0.f, 0.f};
    } else if (b < ZBLK + QBLK) {               // Q path
        int e = (b - ZBLK) * 256 + tid;         // q*8 + k8
        const float4* src = (const float4*)(queries + (size_t)e * 8);
        float4 a = src[0], v = src[1];
        uint4 u;
        u.x = pk2(a.x, a.y); u.y = pk2(a.z, a.w);
        u.z = pk2(v.x, v.y); u.w = pk2(v.z, v.w);
        qpack[e] = u;
    } else {                                    // K path
        int e = (b - ZBLK - QBLK) * 256 + tid;  // slot*8 + k8
        int slot = e >> 3, k8 = e & 7;
        const float4* src = (const float4*)(keys + (size_t)slot * KEY_DIM + k8 * 8);
        float4 a = src[0], v = src[1];
        uint4 u;
        u.x = pk2(a.x, a.y); u.y = pk2(a.z, a.w);
        u.z = pk2(v.x, v.y); u.w = pk2(v.z, v.w);
        int tile = slot >> 7, r = slot & 127;
        kpack[(size_t)tile * 1024 + r * 8 + (k8 ^ (r & 7))] = u;
    }
}

// ---- 1-pass f16 MFMA screen; med3 insert; bias via MFMA C-operand ----
// grid = (chunk=8, qblock=128): id%8 = chunk -> one chunk per XCD (exact);
// a CU's 4 resident blocks {b,b+256,..} share the SAME chunk -> one L1 stream.
// Each wave owns ONE 16-query tile (QPB=64): B-frags halve, j-loop gone.
// id = gid*4+lrow < 2048 (11 bits) -> key mask 0xFFFFF800 (step ~5e-4 << 0.009
// rank-4 spacing). Insert: 1 v_max + 3 v_med3_u32, depth 1.
__global__ __launch_bounds__(256, 4) void k1_screen(
        const uint4* __restrict__ qpack, const uint4* __restrict__ kpack,
        uint32_t* __restrict__ cand) {
    __shared__ uint4 sbuf[2048];                // 32 KiB double buffer

    const int tid = threadIdx.x;
    const int w = tid >> 6, lane = tid & 63;
    const int lcol = lane & 15, lrow = lane >> 4;
    const int chunk  = blockIdx.x;              // 8
    const int qblock = blockIdx.y;              // 128

    f16x8 B[2];
    #pragma unroll
    for (int ks = 0; ks < 2; ++ks) {
        int q = qblock * QPB + w * 16 + lcol;
        F16 t; t.u = qpack[q * 8 + lrow + ks * 4];
        B[ks] = t.h;
    }

    uint32_t kk[4] = {0u, 0u, 0u, 0u};          // packed top-4, desc

    const uint4* gbase = kpack + (size_t)(chunk * TILES_PER_CHUNK) * 1024;
    const int x0 = lrow ^ (lcol & 7);
    const int base_b = lcol * 128 + x0 * 16;
    const f32x4 zacc = {4.0f, 4.0f, 4.0f, 4.0f};   // free bias via C-in

#define STAGE(tt, bb) do {                                                    \
        const uint4* gg = gbase + (size_t)(tt) * 1024 + w * 256 + lane;       \
        char* ldst = (char*)sbuf + (bb) * 16384 + w * 4096;                   \
        _Pragma("unroll")                                                     \
        for (int i_ = 0; i_ < 4; ++i_)                                        \
            gload16((const void*)(gg + i_ * 64), (void*)(ldst + i_ * 1024));  \
    } while (0)

    STAGE(0, 0);

    #pragma unroll 1
    for (int t = 0; t < TILES_PER_CHUNK; ++t) {
        __syncthreads();
        if (t < TILES_PER_CHUNK - 1) STAGE(t + 1, (t + 1) & 1);
        const char* sbb = (const char*)sbuf + (t & 1) * 16384;
        const uint32_t tbase = (uint32_t)(t * 32) + (uint32_t)lrow;

        #pragma unroll
        for (int sub = 0; sub < SUBT; ++sub) {
            uint4 ua0 = *(const uint4*)(sbb + base_b + sub * 2048);
            uint4 ua1 = *(const uint4*)(sbb + (base_b ^ 64) + sub * 2048);
            F16 a0, a1; a0.u = ua0; a1.u = ua1;
            const uint32_t idb = tbase + (uint32_t)(sub * 4);  // (t*8+sub)*4+lrow

            f32x4 acc = __builtin_amdgcn_mfma_f32_16x16x32_f16(a0.h, B[0], zacc, 0, 0, 0);
            acc = __builtin_amdgcn_mfma_f32_16x16x32_f16(a1.h, B[1], acc, 0, 0, 0);
            // nested -> v_max3_f32 + v_max_f32
            float m = fmaxf(fmaxf(fmaxf(acc[0], acc[1]), acc[2]), acc[3]);
            // -> v_and_or_b32 (mask in SGPR); 11-bit id field
            uint32_t key = (__float_as_uint(m) & 0xFFFFF800u) | idb;
            uint32_t t0 = kk[0], t1 = kk[1], t2 = kk[2], t3 = kk[3];
            kk[0] = max(t0, key);
            kk[1] = med3u(t0, t1, key);
            kk[2] = med3u(t1, t2, key);
            kk[3] = med3u(t2, t3, key);
        }
    }
#undef STAGE

    // butterfly-merge the 4 lrow lanes of each query; emit 4 grows per (q,chunk)
    {
        uint32_t s4[4] = {kk[0], kk[1], kk[2], kk[3]};
        #pragma unroll
        for (int m = 16; m <= 32; m <<= 1) {
            uint32_t b0 = (uint32_t)__shfl_xor((int)s4[0], m, 64);
            uint32_t b1 = (uint32_t)__shfl_xor((int)s4[1], m, 64);
            uint32_t b2 = (uint32_t)__shfl_xor((int)s4[2], m, 64);
            uint32_t b3 = (uint32_t)__shfl_xor((int)s4[3], m, 64);
            merge4_32(s4, b0, b1, b2, b3);
        }
        if (lane < 16) {
            int q = qblock * QPB + w * 16 + lane;
            uint4 c;
            c.x = s4[0] & 2047u; c.y = s4[1] & 2047u;
            c.z = s4[2] & 2047u; c.w = s4[3] & 2047u;
            *(uint4*)&cand[((size_t)q * NCHUNK + chunk) * 4] = c;
        }
    }
}

// ---- exact f64 rescore of 128 candidates + fused gather/scatter ----
// 1 wave per query; 4 lanes per key row (64B contiguous each).
__global__ __launch_bounds__(256) void k2_rescore(
        const uint32_t* __restrict__ cand,
        const float* __restrict__ queries, const float* __restrict__ keys,
        const float* __restrict__ vals, const float* __restrict__ grads,
        float* __restrict__ retrieved, float* __restrict__ idx_f,
        float* __restrict__ slot_grads, float* __restrict__ counts) {
    int w = threadIdx.x >> 6, lane = threadIdx.x & 63;
    int q = blockIdx.x * 4 + w;
    int seg = lane & 3;

    const float4* qp = (const float4*)(queries + (size_t)q * KEY_DIM);
    float4 q0 = qp[seg * 4 + 0], q1 = qp[seg * 4 + 1];
    float4 q2 = qp[seg * 4 + 2], q3 = qp[seg * 4 + 3];
    const uint32_t* cq = cand + (size_t)q * 32;

    uint64_t s4[4] = {0ull, 0ull, 0ull, 0ull};
    #pragma unroll 4
    for (int it = 0; it < 8; ++it) {
        int r = it * 16 + (lane >> 2);          // candidate 0..127
        uint32_t grow = cq[r >> 2];             // gid*4 + lrow (11 bits)
        int slot = (r >> 4) * CHUNK + (int)(grow >> 2) * 16
                 + (int)(grow & 3) * 4 + (r & 3);
        const float4* kp = (const float4*)(keys + (size_t)slot * KEY_DIM) + seg * 4;
        float4 k0 = kp[0], k1 = kp[1], k2 = kp[2], k3 = kp[3];
        double ac0 = 0.0, ac1 = 0.0;            // 2 chains: halve dep latency
        ac0 = fma((double)q0.x, (double)k0.x, ac0);
        ac1 = fma((double)q0.y, (double)k0.y, ac1);
        ac0 = fma((double)q0.z, (double)k0.z, ac0);
        ac1 = fma((double)q0.w, (double)k0.w, ac1);
        ac0 = fma((double)q1.x, (double)k1.x, ac0);
        ac1 = fma((double)q1.y, (double)k1.y, ac1);
        ac0 = fma((double)q1.z, (double)k1.z, ac0);
        ac1 = fma((double)q1.w, (double)k1.w, ac1);
        ac0 = fma((double)q2.x, (double)k2.x, ac0);
        ac1 = fma((double)q2.y, (double)k2.y, ac1);
        ac0 = fma((double)q2.z, (double)k2.z, ac0);
        ac1 = fma((double)q2.w, (double)k2.w, ac1);
        ac0 = fma((double)q3.x, (double)k3.x, ac0);
        ac1 = fma((double)q3.y, (double)k3.y, ac1);
        ac0 = fma((double)q3.z, (double)k3.z, ac0);
        ac1 = fma((double)q3.w, (double)k3.w, ac1);
        double acc = ac0 + ac1;
        acc += __shfl_xor(acc, 1, 64);          // combine 4 row segments
        acc += __shfl_xor(acc, 2, 64);
        uint64_t key = (ord64(acc) & 0xFFFFFFFFFFFF0000ull)
                     | (uint64_t)((~(uint32_t)slot) & 0xFFFFu);
        if (seg != 0) key = 0ull;               // one insert per candidate row
        ins4(s4, key);
    }
    #pragma unroll
    for (int m = 1; m <= 32; m <<= 1) {
        uint64_t b0 = (uint64_t)__shfl_xor((unsigned long long)s4[0], m, 64);
        uint64_t b1 = (uint64_t)__shfl_xor((unsigned long long)s4[1], m, 64);
        uint64_t b2 = (uint64_t)__shfl_xor((unsigned long long)s4[2], m, 64);
        uint64_t b3 = (uint64_t)__shfl_xor((unsigned long long)s4[3], m, 64);
        merge4_64(s4, b0, b1, b2, b3);
    }
    // after the full butterfly every lane holds the final top-4
    int sl0 = (int)((~(uint32_t)s4[0]) & 0xFFFFu);
    int sl1 = (int)((~(uint32_t)s4[1]) & 0xFFFFu);
    int sl2 = (int)((~(uint32_t)s4[2]) & 0xFFFFu);
    int sl3 = (int)((~(uint32_t)s4[3]) & 0xFFFFu);
    if (lane == 0) {
        idx_f[q * TOPK + 0] = (float)sl0;
        idx_f[q * TOPK + 1] = (float)sl1;
        idx_f[q * TOPK + 2] = (float)sl2;
        idx_f[q * TOPK + 3] = (float)sl3;
    }
    // fused gather + scatter (64 lanes = 64 dims)
    int slots[4] = {sl0, sl1, sl2, sl3};
    #pragma unroll
    for (int r = 0; r < 4; ++r) {
        int s = slots[r];
        float g = grads[(size_t)q * 256 + r * 64 + lane];
        retrieved[(size_t)q * 256 + r * 64 + lane] = vals[(size_t)s * 64 + lane];
        atomicAdd(&slot_grads[(size_t)s * 64 + lane], g);
        if (lane == 0) atomicAdd(&counts[s], 1.0f);
    }
}

__global__ void k4_update(const float* __restrict__ vals,
                          const float* __restrict__ mom,
                          const float* __restrict__ slot_grads,
                          const float* __restrict__ counts,
                          float* __restrict__ new_vals,
                          float* __restrict__ new_mom) {
    int e4 = blockIdx.x * 256 + threadIdx.x;    // < N_SLOTS*VAL_DIM/4
    int slot = e4 >> 4;                         // 16 float4 per slot row
    float c = counts[slot];
    float4 g  = ((const float4*)slot_grads)[e4];
    float4 mv = ((const float4*)mom)[e4];
    float4 v  = ((const float4*)vals)[e4];
    float inv = 1.0f / fmaxf(c, 1.0f);
    float sel = (c > 0.0f) ? -LR : 0.0f;
    float4 nm, nv;
    nm.x = MOMENTUM * mv.x + g.x * inv;  nv.x = v.x + sel * (nm.x + WD * v.x);
    nm.y = MOMENTUM * mv.y + g.y * inv;  nv.y = v.y + sel * (nm.y + WD * v.y);
    nm.z = MOMENTUM * mv.z + g.z * inv;  nv.z = v.z + sel * (nm.z + WD * v.z);
    nm.w = MOMENTUM * mv.w + g.w * inv;  nv.w = v.w + sel * (nm.w + WD * v.w);
    ((float4*)new_vals)[e4] = nv;
    ((float4*)new_mom)[e4]  = nm;
}

extern "C" void kernel_launch(void* const* d_in, const int* in_sizes, int n_in,
                              void* d_out, int out_size, void* d_ws, size_t ws_size,
                              hipStream_t stream) {
    const float* queries = (const float*)d_in[0];
    const float* grads   = (const float*)d_in[1];
    const float* keys    = (const float*)d_in[2];
    const float* vals    = (const float*)d_in[3];
    const float* mom     = (const float*)d_in[4];

    float* out = (float*)d_out;
    float* retrieved = out;
    float* idx_f     = retrieved + (size_t)N_QUERIES * TOPK * VAL_DIM;
    float* new_vals  = idx_f + (size_t)N_QUERIES * TOPK;
    float* new_mom   = new_vals + (size_t)N_SLOTS * VAL_DIM;

    float*    slot_grads = (float*)d_ws;                            // 16 MiB
    float*    counts     = slot_grads + (size_t)N_SLOTS * VAL_DIM;  // 256 KiB
    uint4*    qpack = (uint4*)(counts + N_SLOTS);                   // 1 MiB
    uint4*    kpack = qpack + (size_t)N_QUERIES * 8;                // 8 MiB
    uint32_t* cand  = (uint32_t*)(kpack + (size_t)(N_SLOTS / TILE_SLOTS) * 1024); // 1 MiB

    hipLaunchKernelGGL(kA_pack, dim3(ZBLK + QBLK + KBLK), dim3(256), 0, stream,
                       queries, keys, qpack, kpack, (float4*)slot_grads);
    hipLaunchKernelGGL(k1_screen, dim3(NCHUNK, N_QUERIES / QPB), dim3(256), 0, stream,
                       qpack, kpack, cand);
    hipLaunchKernelGGL(k2_rescore, dim3(N_QUERIES / 4), dim3(256), 0, stream,
                       cand, queries, keys, vals, grads,
                       retrieved, idx_f, slot_grads, counts);
    hipLaunchKernelGGL(k4_update, dim3(N_SLOTS * VAL_DIM / 4 / 256), dim3(256),
                       0, stream, vals, mom, slot_grads, counts, new_vals, new_mom);
}

// Round 15
// 126.057 us; speedup vs baseline: 1.2420x; 1.2420x over previous
//
#include <hip/hip_runtime.h>
#include <stdint.h>

#define N_SLOTS   65536
#define KEY_DIM   64
#define VAL_DIM   64
#define N_QUERIES 8192
#define TOPK      4
#define LR        1e-3f
#define MOMENTUM  0.9f
#define WD        1e-4f

#define NCHUNK 16
#define CHUNK  (N_SLOTS / NCHUNK)     /* 4096 slots per chunk */
#define TILE_SLOTS 128
#define TILES_PER_CHUNK (CHUNK / TILE_SLOTS)   /* 32 */
#define SUBT 8                         /* 8 subtiles of 16 slots per tile */
#define QPB 128                        /* 4 waves x 2 qtiles x 16 */

/* kA_pack fused grid: zero | Q-pack | K-pack */
#define ZF4   ((N_SLOTS * VAL_DIM + N_SLOTS) / 4)   /* 1,064,960 float4 */
#define ZBLK  (ZF4 / 256)                            /* 4160 exactly */
#define QBLK  (N_QUERIES * 8 / 256)                  /* 256 */
#define KBLK  (N_SLOTS * 8 / 256)                    /* 2048 */

typedef __attribute__((ext_vector_type(8))) _Float16 f16x8;
typedef __attribute__((ext_vector_type(2))) __fp16   fp16x2;
typedef __attribute__((ext_vector_type(4))) float    f32x4;
union F16 { uint4 u; f16x8 h; };
union PK  { fp16x2 h2; uint32_t u; };

__device__ __forceinline__ uint32_t pk2(float a, float b) {
    PK p; p.h2 = __builtin_amdgcn_cvt_pkrtz(a, b); return p.u;
}

__device__ __forceinline__ uint32_t med3u(uint32_t a, uint32_t b, uint32_t c) {
    uint32_t d;
    asm("v_med3_u32 %0, %1, %2, %3" : "=v"(d) : "v"(a), "v"(b), "v"(c));
    return d;
}

__device__ __forceinline__ uint64_t ord64(double d) {
    uint64_t u = (uint64_t)__double_as_longlong(d);
    return (u & 0x8000000000000000ull) ? ~u : (u | 0x8000000000000000ull);
}
__device__ __forceinline__ void cswap64(uint64_t& x, uint64_t& y) {
    uint64_t hi = x > y ? x : y;
    uint64_t lo = x > y ? y : x;
    x = hi; y = lo;
}
__device__ __forceinline__ void merge4_64(uint64_t* a, uint64_t b0, uint64_t b1,
                                          uint64_t b2, uint64_t b3) {
    uint64_t m0 = a[0] > b3 ? a[0] : b3;
    uint64_t m1 = a[1] > b2 ? a[1] : b2;
    uint64_t m2 = a[2] > b1 ? a[2] : b1;
    uint64_t m3 = a[3] > b0 ? a[3] : b0;
    cswap64(m0, m2); cswap64(m1, m3); cswap64(m0, m1); cswap64(m2, m3);
    a[0] = m0; a[1] = m1; a[2] = m2; a[3] = m3;
}
__device__ __forceinline__ void cswap32(uint32_t& x, uint32_t& y) {
    uint32_t hi = max(x, y);
    uint32_t lo = min(x, y);
    x = hi; y = lo;
}
__device__ __forceinline__ void merge4_32(uint32_t* a, uint32_t b0, uint32_t b1,
                                          uint32_t b2, uint32_t b3) {
    uint32_t m0 = max(a[0], b3);
    uint32_t m1 = max(a[1], b2);
    uint32_t m2 = max(a[2], b1);
    uint32_t m3 = max(a[3], b0);
    cswap32(m0, m2); cswap32(m1, m3); cswap32(m0, m1); cswap32(m2, m3);
    a[0] = m0; a[1] = m1; a[2] = m2; a[3] = m3;
}

#define BFLY64(S)                                                             \
    _Pragma("unroll")                                                         \
    for (int m_ = 1; m_ <= 32; m_ <<= 1) {                                    \
        uint64_t b0_ = (uint64_t)__shfl_xor((unsigned long long)S[0], m_, 64);\
        uint64_t b1_ = (uint64_t)__shfl_xor((unsigned long long)S[1], m_, 64);\
        uint64_t b2_ = (uint64_t)__shfl_xor((unsigned long long)S[2], m_, 64);\
        uint64_t b3_ = (uint64_t)__shfl_xor((unsigned long long)S[3], m_, 64);\
        merge4_64(S, b0_, b1_, b2_, b3_);                                     \
    }

__device__ __forceinline__ void gload16(const void* g, void* l) {
    __builtin_amdgcn_global_load_lds(
        (const __attribute__((address_space(1))) uint32_t*)g,
        (__attribute__((address_space(3))) uint32_t*)l, 16, 0, 0);
}

// ---- fused: zero slot_grads/counts + f32->f16 pack (Q row-major, K swizzled) ----
// kpack unit = tile*1024 + r*8 + (k8 ^ (r&7)),  tile = slot/128, r = slot%128
__global__ void kA_pack(const float* __restrict__ queries,
                        const float* __restrict__ keys,
                        uint4* __restrict__ qpack, uint4* __restrict__ kpack,
                        float4* __restrict__ zbuf) {
    const int b = blockIdx.x, tid = threadIdx.x;
    if (b < ZBLK) {                             // zero slot_grads + counts
        zbuf[b * 256 + tid] = (float4){0.f, 0.f, 0.f, 0.f};
    } else if (b < ZBLK + QBLK) {               // Q path
        int e = (b - ZBLK) * 256 + tid;         // q*8 + k8
        const float4* src = (const float4*)(queries + (size_t)e * 8);
        float4 a = src[0], v = src[1];
        uint4 u;
        u.x = pk2(a.x, a.y); u.y = pk2(a.z, a.w);
        u.z = pk2(v.x, v.y); u.w = pk2(v.z, v.w);
        qpack[e] = u;
    } else {                                    // K path
        int e = (b - ZBLK - QBLK) * 256 + tid;  // slot*8 + k8
        int slot = e >> 3, k8 = e & 7;
        const float4* src = (const float4*)(keys + (size_t)slot * KEY_DIM + k8 * 8);
        float4 a = src[0], v = src[1];
        uint4 u;
        u.x = pk2(a.x, a.y); u.y = pk2(a.z, a.w);
        u.z = pk2(v.x, v.y); u.w = pk2(v.z, v.w);
        int tile = slot >> 7, r = slot & 127;
        kpack[(size_t)tile * 1024 + r * 8 + (k8 ^ (r & 7))] = u;
    }
}

// ---- 1-pass f16 MFMA screen (r13 config: NCHUNK=16, QPB=128, j-loop) ----
// grid = (chunk=16, qblock=64): id%8 = chunk%8 -> chunk pinned to one XCD;
// a CU's 4 resident blocks all share the SAME chunk -> one tile stream in L1.
// j-loop keeps K-fragment reuse (2 ds_read feed 4 MFMA) + dual dep chains
// (r14 lesson: QPB=64 doubled LDS issue, k1 88.8 -> 107 us).
// Emit: FULL 32-bit keys (score|10-bit id) -- k2 uses scores for global top-8.
__global__ __launch_bounds__(256, 4) void k1_screen(
        const uint4* __restrict__ qpack, const uint4* __restrict__ kpack,
        uint32_t* __restrict__ cand) {
    __shared__ uint4 sbuf[2048];                // 32 KiB double buffer

    const int tid = threadIdx.x;
    const int w = tid >> 6, lane = tid & 63;
    const int lcol = lane & 15, lrow = lane >> 4;
    const int chunk  = blockIdx.x;              // 16
    const int qblock = blockIdx.y;              // 64

    f16x8 B[2][2];
    #pragma unroll
    for (int j = 0; j < 2; ++j) {
        #pragma unroll
        for (int ks = 0; ks < 2; ++ks) {
            int q = qblock * QPB + w * 32 + j * 16 + lcol;
            F16 t; t.u = qpack[q * 8 + lrow + ks * 4];
            B[j][ks] = t.h;
        }
    }

    uint32_t kk[2][4] = {{0u,0u,0u,0u},{0u,0u,0u,0u}};   // packed top-4, desc

    const uint4* gbase = kpack + (size_t)(chunk * TILES_PER_CHUNK) * 1024;
    const int x0 = lrow ^ (lcol & 7);
    const int base_b = lcol * 128 + x0 * 16;
    const f32x4 zacc = {4.0f, 4.0f, 4.0f, 4.0f};   // free bias via C-in

#define STAGE(tt, bb) do {                                                    \
        const uint4* gg = gbase + (size_t)(tt) * 1024 + w * 256 + lane;       \
        char* ldst = (char*)sbuf + (bb) * 16384 + w * 4096;                   \
        _Pragma("unroll")                                                     \
        for (int i_ = 0; i_ < 4; ++i_)                                        \
            gload16((const void*)(gg + i_ * 64), (void*)(ldst + i_ * 1024));  \
    } while (0)

    STAGE(0, 0);

    #pragma unroll 1
    for (int t = 0; t < TILES_PER_CHUNK; ++t) {
        __syncthreads();
        if (t < TILES_PER_CHUNK - 1) STAGE(t + 1, (t + 1) & 1);
        const char* sbb = (const char*)sbuf + (t & 1) * 16384;
        const uint32_t tbase = (uint32_t)(t * 32) + (uint32_t)lrow;

        #pragma unroll
        for (int sub = 0; sub < SUBT; ++sub) {
            uint4 ua0 = *(const uint4*)(sbb + base_b + sub * 2048);
            uint4 ua1 = *(const uint4*)(sbb + (base_b ^ 64) + sub * 2048);
            F16 a0, a1; a0.u = ua0; a1.u = ua1;
            const uint32_t idb = tbase + (uint32_t)(sub * 4);  // (t*8+sub)*4+lrow

            #pragma unroll
            for (int j = 0; j < 2; ++j) {
                f32x4 acc = __builtin_amdgcn_mfma_f32_16x16x32_f16(a0.h, B[j][0], zacc, 0, 0, 0);
                acc = __builtin_amdgcn_mfma_f32_16x16x32_f16(a1.h, B[j][1], acc, 0, 0, 0);
                // nested -> v_max3_f32 + v_max_f32
                float m = fmaxf(fmaxf(fmaxf(acc[0], acc[1]), acc[2]), acc[3]);
                // -> v_and_or_b32 (mask in SGPR)
                uint32_t key = (__float_as_uint(m) & 0xFFFFFC00u) | idb;
                uint32_t t0 = kk[j][0], t1 = kk[j][1], t2 = kk[j][2], t3 = kk[j][3];
                kk[j][0] = max(t0, key);
                kk[j][1] = med3u(t0, t1, key);
                kk[j][2] = med3u(t1, t2, key);
                kk[j][3] = med3u(t2, t3, key);
            }
        }
    }
#undef STAGE

    // butterfly-merge the 4 lrow lanes of each query; emit 4 FULL keys per (q,chunk)
    #pragma unroll
    for (int j = 0; j < 2; ++j) {
        uint32_t s4[4] = {kk[j][0], kk[j][1], kk[j][2], kk[j][3]};
        #pragma unroll
        for (int m = 16; m <= 32; m <<= 1) {
            uint32_t b0 = (uint32_t)__shfl_xor((int)s4[0], m, 64);
            uint32_t b1 = (uint32_t)__shfl_xor((int)s4[1], m, 64);
            uint32_t b2 = (uint32_t)__shfl_xor((int)s4[2], m, 64);
            uint32_t b3 = (uint32_t)__shfl_xor((int)s4[3], m, 64);
            merge4_32(s4, b0, b1, b2, b3);
        }
        if (lane < 16) {
            int q = qblock * QPB + w * 32 + j * 16 + lane;
            uint4 c;
            c.x = s4[0]; c.y = s4[1]; c.z = s4[2]; c.w = s4[3];
            *(uint4*)&cand[((size_t)q * NCHUNK + chunk) * 4] = c;
        }
    }
}

// ---- global top-8 id-rows by screened key, then exact f64 rescore of 32 ----
// 1 wave per query. Each candidate id-row = 4 slots; 2 lanes per slot row.
__global__ __launch_bounds__(256) void k2_rescore(
        const uint32_t* __restrict__ cand,
        const float* __restrict__ queries, const float* __restrict__ keys,
        const float* __restrict__ vals, const float* __restrict__ grads,
        float* __restrict__ retrieved, float* __restrict__ idx_f,
        float* __restrict__ slot_grads, float* __restrict__ counts) {
    int w = threadIdx.x >> 6, lane = threadIdx.x & 63;
    int q = blockIdx.x * 4 + w;

    // lane <-> (chunk = lane>>2, e = lane&3): one screened key per lane
    uint32_t key32 = cand[(size_t)q * 64 + lane];
    uint64_t aug = ((uint64_t)key32 << 14)
                 | (uint64_t)((uint32_t)(lane >> 2) << 10)
                 | (uint64_t)(key32 & 1023u);
    uint64_t s4[4] = {aug, 0ull, 0ull, 0ull};
    BFLY64(s4);                                  // global top-4 (all lanes)
    uint64_t aug2 = (aug == s4[0] || aug == s4[1] ||
                     aug == s4[2] || aug == s4[3]) ? 0ull : aug;
    uint64_t r4[4] = {aug2, 0ull, 0ull, 0ull};
    BFLY64(r4);                                  // ranks 5..8 (all lanes)

    // decode candidate: r = lane>>1 in 0..31 -> id-row g = r>>2, slot rr = r&3
    int r = lane >> 1, seg = lane & 1;
    int g = r >> 2, rr = r & 3;
    uint64_t tg = g == 0 ? s4[0] : g == 1 ? s4[1] : g == 2 ? s4[2] : g == 3 ? s4[3]
                : g == 4 ? r4[0] : g == 5 ? r4[1] : g == 6 ? r4[2] : r4[3];
    uint32_t low = (uint32_t)tg & 0x3FFFu;
    int chn = (int)(low >> 10);
    int id  = (int)(low & 1023u);               // t*32 + sub*4 + lrow
    int slot = chn * CHUNK + (id >> 2) * 16 + (id & 3) * 4 + rr;

    const float4* qp = (const float4*)(queries + (size_t)q * KEY_DIM) + seg * 8;
    const float4* kp = (const float4*)(keys + (size_t)slot * KEY_DIM) + seg * 8;
    double ac0 = 0.0, ac1 = 0.0;
    #pragma unroll
    for (int u = 0; u < 8; ++u) {
        float4 qv = qp[u], kv = kp[u];
        ac0 = fma((double)qv.x, (double)kv.x, ac0);
        ac1 = fma((double)qv.y, (double)kv.y, ac1);
        ac0 = fma((double)qv.z, (double)kv.z, ac0);
        ac1 = fma((double)qv.w, (double)kv.w, ac1);
    }
    double acc = ac0 + ac1;
    acc += __shfl_xor(acc, 1, 64);              // combine the 2 row halves
    uint64_t fkey = (ord64(acc) & 0xFFFFFFFFFFFF0000ull)
                  | (uint64_t)((~(uint32_t)slot) & 0xFFFFu);
    if (seg != 0) fkey = 0ull;                  // one key per candidate slot
    uint64_t f4[4] = {fkey, 0ull, 0ull, 0ull};
    BFLY64(f4);                                  // final exact top-4 (all lanes)

    int sl0 = (int)((~(uint32_t)f4[0]) & 0xFFFFu);
    int sl1 = (int)((~(uint32_t)f4[1]) & 0xFFFFu);
    int sl2 = (int)((~(uint32_t)f4[2]) & 0xFFFFu);
    int sl3 = (int)((~(uint32_t)f4[3]) & 0xFFFFu);
    if (lane == 0) {
        idx_f[q * TOPK + 0] = (float)sl0;
        idx_f[q * TOPK + 1] = (float)sl1;
        idx_f[q * TOPK + 2] = (float)sl2;
        idx_f[q * TOPK + 3] = (float)sl3;
    }
    // fused gather + scatter (64 lanes = 64 dims)
    int slots[4] = {sl0, sl1, sl2, sl3};
    #pragma unroll
    for (int rr2 = 0; rr2 < 4; ++rr2) {
        int s = slots[rr2];
        float gg = grads[(size_t)q * 256 + rr2 * 64 + lane];
        retrieved[(size_t)q * 256 + rr2 * 64 + lane] = vals[(size_t)s * 64 + lane];
        atomicAdd(&slot_grads[(size_t)s * 64 + lane], gg);
        if (lane == 0) atomicAdd(&counts[s], 1.0f);
    }
}

__global__ void k4_update(const float* __restrict__ vals,
                          const float* __restrict__ mom,
                          const float* __restrict__ slot_grads,
                          const float* __restrict__ counts,
                          float* __restrict__ new_vals,
                          float* __restrict__ new_mom) {
    int e4 = blockIdx.x * 256 + threadIdx.x;    // < N_SLOTS*VAL_DIM/4
    int slot = e4 >> 4;                         // 16 float4 per slot row
    float c = counts[slot];
    float4 g  = ((const float4*)slot_grads)[e4];
    float4 mv = ((const float4*)mom)[e4];
    float4 v  = ((const float4*)vals)[e4];
    float inv = 1.0f / fmaxf(c, 1.0f);
    float sel = (c > 0.0f) ? -LR : 0.0f;
    float4 nm, nv;
    nm.x = MOMENTUM * mv.x + g.x * inv;  nv.x = v.x + sel * (nm.x + WD * v.x);
    nm.y = MOMENTUM * mv.y + g.y * inv;  nv.y = v.y + sel * (nm.y + WD * v.y);
    nm.z = MOMENTUM * mv.z + g.z * inv;  nv.z = v.z + sel * (nm.z + WD * v.z);
    nm.w = MOMENTUM * mv.w + g.w * inv;  nv.w = v.w + sel * (nm.w + WD * v.w);
    ((float4*)new_vals)[e4] = nv;
    ((float4*)new_mom)[e4]  = nm;
}

extern "C" void kernel_launch(void* const* d_in, const int* in_sizes, int n_in,
                              void* d_out, int out_size, void* d_ws, size_t ws_size,
                              hipStream_t stream) {
    const float* queries = (const float*)d_in[0];
    const float* grads   = (const float*)d_in[1];
    const float* keys    = (const float*)d_in[2];
    const float* vals    = (const float*)d_in[3];
    const float* mom     = (const float*)d_in[4];

    float* out = (float*)d_out;
    float* retrieved = out;
    float* idx_f     = retrieved + (size_t)N_QUERIES * TOPK * VAL_DIM;
    float* new_vals  = idx_f + (size_t)N_QUERIES * TOPK;
    float* new_mom   = new_vals + (size_t)N_SLOTS * VAL_DIM;

    float*    slot_grads = (float*)d_ws;                            // 16 MiB
    float*    counts     = slot_grads + (size_t)N_SLOTS * VAL_DIM;  // 256 KiB
    uint4*    qpack = (uint4*)(counts + N_SLOTS);                   // 1 MiB
    uint4*    kpack = qpack + (size_t)N_QUERIES * 8;                // 8 MiB
    uint32_t* cand  = (uint32_t*)(kpack + (size_t)(N_SLOTS / TILE_SLOTS) * 1024); // 2 MiB

    hipLaunchKernelGGL(kA_pack, dim3(ZBLK + QBLK + KBLK), dim3(256), 0, stream,
                       queries, keys, qpack, kpack, (float4*)slot_grads);
    hipLaunchKernelGGL(k1_screen, dim3(NCHUNK, N_QUERIES / QPB), dim3(256), 0, stream,
                       qpack, kpack, cand);
    hipLaunchKernelGGL(k2_rescore, dim3(N_QUERIES / 4), dim3(256), 0, stream,
                       cand, queries, keys, vals, grads,
                       retrieved, idx_f, slot_grads, counts);
    hipLaunchKernelGGL(k4_update, dim3(N_SLOTS * VAL_DIM / 4 / 256), dim3(256),
                       0, stream, vals, mom, slot_grads, counts, new_vals, new_mom);
}